// Round 16
// baseline (292.226 us; speedup 1.0000x reference)
//
#include <hip/hip_runtime.h>

#define NN 50000
#define IN_DIM 128
#define HID 64
#define NLAYERS 3
#define NB 1563      // ceil(NN/32) bins (bin = dst>>5)
#define CH 128       // edge chunks
#define NPART 8      // XCD partitions for scatter
#define BPP 196      // bins per partition (8*196 >= NB)
#define PQ_BLOCKS 782

typedef __attribute__((ext_vector_type(8))) _Float16 f16x8;
typedef __attribute__((ext_vector_type(2))) _Float16 f16x2;
typedef __attribute__((ext_vector_type(4))) float f32x4;

__device__ __forceinline__ unsigned pkh(float a, float b) {
    return __builtin_bit_cast(unsigned, __builtin_amdgcn_cvt_pkrtz(a, b));
}
__device__ __forceinline__ unsigned short f2h(float f) {
    f16x2 v = __builtin_bit_cast(f16x2, __builtin_amdgcn_cvt_pkrtz(f, 0.f));
    return __builtin_bit_cast(short2, v).x;
}
__device__ __forceinline__ float h2f(unsigned short u) {
    return (float)__builtin_bit_cast(_Float16, u);
}

// packed f16: relu(q + p) in 2 VALU ops (v_pk_add_f16 + v_pk_max_f16).
__device__ __forceinline__ unsigned addrelu2(unsigned q, unsigned p) {
    f16x2 qq = __builtin_bit_cast(f16x2, q);
    f16x2 pp = __builtin_bit_cast(f16x2, p);
    f16x2 s = qq + pp;
    f16x2 z = {(_Float16)0.f, (_Float16)0.f};
    f16x2 r = __builtin_elementwise_max(s, z);
    return __builtin_bit_cast(unsigned, r);
}

// ---- CSR build (R11 structure, unchanged) ----

__global__ void __launch_bounds__(256) k_hist(const int* __restrict__ dst,
                                              int* __restrict__ cntc, int E, int CE) {
    __shared__ int lh[NB];
    int g = blockIdx.x;
    for (int i = threadIdx.x; i < NB; i += 256) lh[i] = 0;
    __syncthreads();
    int e0 = g * CE, e1 = min(E, e0 + CE);
    for (int e = e0 + threadIdx.x; e < e1; e += 256) atomicAdd(&lh[dst[e] >> 5], 1);
    __syncthreads();
    for (int i = threadIdx.x; i < NB; i += 256) cntc[g * NB + i] = lh[i];
}

__global__ void k_base(const int* __restrict__ cntc, int* __restrict__ basec,
                       int* __restrict__ bincnt) {
    int b = blockIdx.x * 256 + threadIdx.x;
    if (b < NB) {
        int run = 0;
        for (int g = 0; g < CH; g++) {
            basec[g * NB + b] = run;
            run += cntc[g * NB + b];
        }
        bincnt[b] = run;
    }
}

__global__ void k_binscan(const int* __restrict__ bincnt, int* __restrict__ binoff) {
    __shared__ int s[256];
    int t = threadIdx.x;
    int carry = 0;
    for (int c0 = 0; c0 < NB; c0 += 256) {
        int v = (c0 + t < NB) ? bincnt[c0 + t] : 0;
        s[t] = v;
        __syncthreads();
        for (int d = 1; d < 256; d <<= 1) {
            int a = (t >= d) ? s[t - d] : 0;
            __syncthreads();
            s[t] += a;
            __syncthreads();
        }
        if (c0 + t < NB) binoff[c0 + t] = carry + s[t] - v;
        carry += s[255];
        __syncthreads();
    }
}

__global__ void __launch_bounds__(256) k_scatter(
    const int* __restrict__ src, const int* __restrict__ dst,
    const int* __restrict__ basec, const int* __restrict__ binoff,
    unsigned* __restrict__ bscratch, int E, int CE) {
    __shared__ int cur[BPP];
    int p = blockIdx.x & (NPART - 1);
    int g = blockIdx.x >> 3;
    int blo = p * BPP, bhi = min(NB, blo + BPP);
    for (int i = threadIdx.x; i < bhi - blo; i += 256) {
        int b = blo + i;
        cur[i] = binoff[b] + basec[g * NB + b];
    }
    __syncthreads();
    int e0 = g * CE, e1 = min(E, e0 + CE);
    for (int e = e0 + threadIdx.x; e < e1; e += 256) {
        int d = dst[e];
        int bin = d >> 5;
        if (bin >= blo && bin < bhi) {
            int pos = atomicAdd(&cur[bin - blo], 1);
            bscratch[pos] = ((unsigned)(d & 31) << 16) | (unsigned)src[e];
        }
    }
}

__global__ void __launch_bounds__(256) k_binsort(
    const unsigned* __restrict__ bscratch, const int* __restrict__ bincnt,
    const int* __restrict__ binoff, unsigned short* __restrict__ csr,
    int2* __restrict__ meta) {
    __shared__ unsigned entries[1024];
    __shared__ unsigned short sorted[1024];
    __shared__ int cnt[32];
    int bin = blockIdx.x, t = threadIdx.x;
    int n = bincnt[bin], boff = binoff[bin];
    for (int i = t; i < n; i += 256) entries[i] = bscratch[boff + i];
    if (t < 32) cnt[t] = 0;
    __syncthreads();
    for (int i = t; i < n; i += 256) atomicAdd(&cnt[entries[i] >> 16], 1);
    __syncthreads();
    if (t < 32) {
        int c = cnt[t];
        int s = c;
#pragma unroll
        for (int d = 1; d < 32; d <<= 1) {
            int o = __shfl_up(s, d, 64);
            if (t >= d) s += o;
        }
        int node = bin * 32 + t;
        if (node < NN) meta[node] = make_int2(boff + s - c, c);
        cnt[t] = s - c;  // reuse as cursor
    }
    __syncthreads();
    for (int i = t; i < n; i += 256) {
        unsigned e = entries[i];
        int p = atomicAdd(&cnt[e >> 16], 1);
        sorted[p] = (unsigned short)(e & 0xffffu);
    }
    __syncthreads();
    for (int i = t; i < n; i += 256) csr[boff + i] = sorted[i];
}

// ---- dense pipeline: f16 h/P/Q, f16 MFMA ----

// Fused: h = x @ Wp + bp (MFMA, x cast f16), then layer-0
// [P|Q] = h @ [W1top-W1bot | W1bot] + [b1|0] (MFMA), h staged per-wave in LDS.
__global__ void __launch_bounds__(256) k_projpq(
    const float* __restrict__ x, const float* __restrict__ Wp,
    const float* __restrict__ bp, const float* __restrict__ W1,
    const float* __restrict__ b1, unsigned short* __restrict__ h,
    unsigned short* __restrict__ P, unsigned short* __restrict__ Qb) {
    __shared__ float hs[4][16][66];  // 16.9 KB; stride 66 -> <=4-way b64 reads
    int lane = threadIdx.x & 63, wave = threadIdx.x >> 6;
    int col = lane & 15, quad = lane >> 4;
    int node0 = (blockIdx.x * 4 + wave) * 16;
    if (node0 >= NN) return;  // wave-uniform; no cross-wave barriers used

    f16x8 bw[4][4];
#pragma unroll
    for (int t = 0; t < 4; t++)
#pragma unroll
        for (int kc = 0; kc < 4; kc++) {
            uint4 u;
#pragma unroll
            for (int jp = 0; jp < 4; jp++) {
                int k0 = kc * 32 + quad * 8 + jp * 2;
                ((unsigned*)&u)[jp] = pkh(Wp[k0 * HID + t * 16 + col],
                                          Wp[(k0 + 1) * HID + t * 16 + col]);
            }
            bw[t][kc] = __builtin_bit_cast(f16x8, u);
        }
    const float4* xr = (const float4*)(x + (size_t)(node0 + col) * IN_DIM);
    f16x8 ax[4];
#pragma unroll
    for (int kc = 0; kc < 4; kc++) {
        float4 f0 = xr[kc * 8 + quad * 2], f1 = xr[kc * 8 + quad * 2 + 1];
        uint4 u;
        u.x = pkh(f0.x, f0.y); u.y = pkh(f0.z, f0.w);
        u.z = pkh(f1.x, f1.y); u.w = pkh(f1.z, f1.w);
        ax[kc] = __builtin_bit_cast(f16x8, u);
    }
#pragma unroll
    for (int t = 0; t < 4; t++) {
        f32x4 c = (f32x4)(0.f);
#pragma unroll
        for (int kc = 0; kc < 4; kc++)
            c = __builtin_amdgcn_mfma_f32_16x16x32_f16(ax[kc], bw[t][kc], c, 0, 0, 0);
        float bv = bp[t * 16 + col];
#pragma unroll
        for (int r = 0; r < 4; r++) {
            float hv = c[r] + bv;
            int row = quad * 4 + r;
            h[(size_t)(node0 + row) * HID + t * 16 + col] = f2h(hv);
            hs[wave][row][t * 16 + col] = hv;
        }
    }

    f16x8 bfr[8][2];
#pragma unroll
    for (int t = 0; t < 8; t++)
#pragma unroll
        for (int hf = 0; hf < 2; hf++) {
            uint4 u;
#pragma unroll
            for (int jp = 0; jp < 4; jp++) {
                int k0 = hf * 32 + quad * 8 + jp * 2;
                float w0, w1v;
                if (t < 4) {
                    int n = t * 16 + col;
                    w0  = W1[k0 * HID + n] - W1[(HID + k0) * HID + n];
                    w1v = W1[(k0 + 1) * HID + n] - W1[(HID + k0 + 1) * HID + n];
                } else {
                    int n = (t - 4) * 16 + col;
                    w0  = W1[(HID + k0) * HID + n];
                    w1v = W1[(HID + k0 + 1) * HID + n];
                }
                ((unsigned*)&u)[jp] = pkh(w0, w1v);
            }
            bfr[t][hf] = __builtin_bit_cast(f16x8, u);
        }
    const float* hl = &hs[wave][col][0];
    uint4 au, bu;
    {
        float2 e0 = *(const float2*)(hl + quad * 8);
        float2 e1 = *(const float2*)(hl + quad * 8 + 2);
        float2 e2 = *(const float2*)(hl + quad * 8 + 4);
        float2 e3 = *(const float2*)(hl + quad * 8 + 6);
        au.x = pkh(e0.x, e0.y); au.y = pkh(e1.x, e1.y);
        au.z = pkh(e2.x, e2.y); au.w = pkh(e3.x, e3.y);
        float2 f0 = *(const float2*)(hl + 32 + quad * 8);
        float2 f1 = *(const float2*)(hl + 32 + quad * 8 + 2);
        float2 f2 = *(const float2*)(hl + 32 + quad * 8 + 4);
        float2 f3 = *(const float2*)(hl + 32 + quad * 8 + 6);
        bu.x = pkh(f0.x, f0.y); bu.y = pkh(f1.x, f1.y);
        bu.z = pkh(f2.x, f2.y); bu.w = pkh(f3.x, f3.y);
    }
    f16x8 a0 = __builtin_bit_cast(f16x8, au);
    f16x8 a1 = __builtin_bit_cast(f16x8, bu);
#pragma unroll
    for (int t = 0; t < 8; t++) {
        f32x4 c = __builtin_amdgcn_mfma_f32_16x16x32_f16(a0, bfr[t][0], (f32x4)(0.f), 0, 0, 0);
        c = __builtin_amdgcn_mfma_f32_16x16x32_f16(a1, bfr[t][1], c, 0, 0, 0);
        if (t < 4) {
            float bv = b1[t * 16 + col];
#pragma unroll
            for (int r = 0; r < 4; r++)
                P[(size_t)(node0 + quad * 4 + r) * HID + t * 16 + col] = f2h(c[r] + bv);
        } else {
#pragma unroll
            for (int r = 0; r < 4; r++)
                Qb[(size_t)(node0 + quad * 4 + r) * HID + (t - 4) * 16 + col] = f2h(c[r]);
        }
    }
}

// [P|Q] = h @ [W1top-W1bot | W1bot] + [b1|0] via MFMA (layers 1,2).
// h is f16: A-fragments are direct uint4 reinterprets of the h row.
__global__ void __launch_bounds__(256) k_pq_mfma(
    const unsigned short* __restrict__ h, const float* __restrict__ W1,
    const float* __restrict__ b1, unsigned short* __restrict__ P,
    unsigned short* __restrict__ Qb, int layer) {
    int lane = threadIdx.x & 63, wave = threadIdx.x >> 6;
    int col = lane & 15, quad = lane >> 4;
    int node0 = (blockIdx.x * 4 + wave) * 16;
    if (node0 >= NN) return;
    const float* W1l = W1 + layer * 2 * HID * HID;

    f16x8 bfr[8][2];
#pragma unroll
    for (int t = 0; t < 8; t++)
#pragma unroll
        for (int hf = 0; hf < 2; hf++) {
            uint4 u;
#pragma unroll
            for (int jp = 0; jp < 4; jp++) {
                int k0 = hf * 32 + quad * 8 + jp * 2;
                float w0, w1v;
                if (t < 4) {
                    int n = t * 16 + col;
                    w0  = W1l[k0 * HID + n] - W1l[(HID + k0) * HID + n];
                    w1v = W1l[(k0 + 1) * HID + n] - W1l[(HID + k0 + 1) * HID + n];
                } else {
                    int n = (t - 4) * 16 + col;
                    w0  = W1l[(HID + k0) * HID + n];
                    w1v = W1l[(HID + k0 + 1) * HID + n];
                }
                ((unsigned*)&u)[jp] = pkh(w0, w1v);
            }
            bfr[t][hf] = __builtin_bit_cast(f16x8, u);
        }

    const uint4* hrow = (const uint4*)(h + (size_t)(node0 + col) * HID);
    uint4 au = hrow[quad];      // k in [quad*8, +8)
    uint4 bu = hrow[4 + quad];  // k in [32+quad*8, +8)
    f16x8 a0 = __builtin_bit_cast(f16x8, au);
    f16x8 a1 = __builtin_bit_cast(f16x8, bu);

#pragma unroll
    for (int t = 0; t < 8; t++) {
        f32x4 c = __builtin_amdgcn_mfma_f32_16x16x32_f16(a0, bfr[t][0], (f32x4)(0.f), 0, 0, 0);
        c = __builtin_amdgcn_mfma_f32_16x16x32_f16(a1, bfr[t][1], c, 0, 0, 0);
        if (t < 4) {
            float bv = b1[layer * HID + t * 16 + col];
#pragma unroll
            for (int r = 0; r < 4; r++)
                P[(size_t)(node0 + quad * 4 + r) * HID + t * 16 + col] = f2h(c[r] + bv);
        } else {
#pragma unroll
            for (int r = 0; r < 4; r++)
                Qb[(size_t)(node0 + quad * 4 + r) * HID + (t - 4) * 16 + col] = f2h(c[r]);
        }
    }
}

// One wave per dst node (grid-stride). 16 edges/batch via mfma_f32_16x16x32_f16.
// Direct A-layout gather (no LDS stage): lane (col,quad) loads its col-edge's
// row segments straight into A-fragment registers. One-deep batch prefetch in
// registers + node-level prefetch of next meta/res (independent loads).
__global__ void __launch_bounds__(256) k_edge(
    const unsigned short* __restrict__ P, const unsigned short* __restrict__ Qb,
    const float* __restrict__ W2, const float* __restrict__ b2,
    const int2* __restrict__ meta, const unsigned short* __restrict__ csr,
    unsigned short* __restrict__ h, int layer, int nw,
    int fin, const float* __restrict__ Wo, const float* __restrict__ bo,
    float* __restrict__ outp) {
    int lane = threadIdx.x & 63;
    int col = lane & 15, quad = lane >> 4;
    int wid = (blockIdx.x * blockDim.x + threadIdx.x) >> 6;

    const float* W2l = W2 + layer * HID * HID;
    f16x8 bfr[4][2];
#pragma unroll
    for (int t = 0; t < 4; t++)
#pragma unroll
        for (int hf = 0; hf < 2; hf++) {
            uint4 u;
#pragma unroll
            for (int jp = 0; jp < 4; jp++) {
                int k0 = hf * 32 + quad * 8 + jp * 2;
                ((unsigned*)&u)[jp] = pkh(W2l[k0 * HID + t * 16 + col],
                                          W2l[(k0 + 1) * HID + t * 16 + col]);
            }
            bfr[t][hf] = __builtin_bit_cast(f16x8, u);
        }
    float b2v = b2[layer * HID + lane];
    float wov = fin ? Wo[lane] : 0.f;

    if (wid >= NN) return;
    int2 md = meta[wid];
    unsigned short hres = h[(size_t)wid * HID + lane];

    for (int node = wid; node < NN; node += nw) {
        // prefetch next node's meta + residual (independent of current work)
        int pf = (node + nw < NN) ? node + nw : node;
        int2 nmd = meta[pf];
        unsigned short nhres = h[(size_t)pf * HID + lane];

        int start = __builtin_amdgcn_readfirstlane(md.x);
        int cnt   = __builtin_amdgcn_readfirstlane(md.y);
        float res = h2f(hres);
        float outv = 0.f;
        if (cnt > 0) {
            const uint4* prow = (const uint4*)(P + (size_t)node * HID);
            uint4 p0 = prow[quad];      // k in [quad*8, +8)
            uint4 p1 = prow[4 + quad];  // k in [32+quad*8, +8)
            f32x4 mx[4];
#pragma unroll
            for (int t = 0; t < 4; t++) mx[t] = (f32x4)(-3.4e38f);
            int nbatch = (cnt + 15) >> 4;
            // batch-0 gather straight into A-layout registers
            int s = csr[start + (col < cnt ? col : 0)];
            const uint4* qr = (const uint4*)(Qb + (size_t)s * HID);
            uint4 q0 = qr[quad], q1 = qr[4 + quad];
            for (int b = 0; b < nbatch; b++) {
                uint4 nq0, nq1;
                if (b + 1 < nbatch) {  // one-deep prefetch of next batch
                    int b0 = (b + 1) * 16;
                    int idx = b0 + col;
                    int s2 = csr[start + (idx < cnt ? idx : b0)];
                    const uint4* qr2 = (const uint4*)(Qb + (size_t)s2 * HID);
                    nq0 = qr2[quad];
                    nq1 = qr2[4 + quad];
                }
                uint4 a0u, a1u;
                a0u.x = addrelu2(q0.x, p0.x);
                a0u.y = addrelu2(q0.y, p0.y);
                a0u.z = addrelu2(q0.z, p0.z);
                a0u.w = addrelu2(q0.w, p0.w);
                a1u.x = addrelu2(q1.x, p1.x);
                a1u.y = addrelu2(q1.y, p1.y);
                a1u.z = addrelu2(q1.z, p1.z);
                a1u.w = addrelu2(q1.w, p1.w);
                f16x8 a0 = __builtin_bit_cast(f16x8, a0u);
                f16x8 a1 = __builtin_bit_cast(f16x8, a1u);
#pragma unroll
                for (int t = 0; t < 4; t++) {
                    f32x4 c = __builtin_amdgcn_mfma_f32_16x16x32_f16(
                        a0, bfr[t][0], (f32x4)(0.f), 0, 0, 0);
                    c = __builtin_amdgcn_mfma_f32_16x16x32_f16(
                        a1, bfr[t][1], c, 0, 0, 0);
#pragma unroll
                    for (int r = 0; r < 4; r++)
                        mx[t][r] = fmaxf(mx[t][r], c[r]);
                }
                q0 = nq0;
                q1 = nq1;
            }
            float v[4];
#pragma unroll
            for (int t = 0; t < 4; t++) {
                v[t] = fmaxf(fmaxf(mx[t][0], mx[t][1]), fmaxf(mx[t][2], mx[t][3]));
                v[t] = fmaxf(v[t], __shfl_xor(v[t], 16, 64));
                v[t] = fmaxf(v[t], __shfl_xor(v[t], 32, 64));
            }
            float vs = quad == 0 ? v[0] : quad == 1 ? v[1] : quad == 2 ? v[2] : v[3];
            outv = fmaxf(vs + b2v, 0.f);
        }
        float hv = outv + res;
        h[(size_t)node * HID + lane] = f2h(hv);
        if (fin) {
            float v = hv * wov;
#pragma unroll
            for (int m = 32; m >= 1; m >>= 1) v += __shfl_xor(v, m, 64);
            if (lane == 0) outp[node] = v + bo[0];
        }
        md = nmd;
        hres = nhres;
    }
}

extern "C" void kernel_launch(void* const* d_in, const int* in_sizes, int n_in,
                              void* d_out, int out_size, void* d_ws, size_t ws_size,
                              hipStream_t stream) {
    const float* x  = (const float*)d_in[0];
    const int*   ei = (const int*)d_in[1];
    const float* Wp = (const float*)d_in[2];
    const float* bp = (const float*)d_in[3];
    const float* W1 = (const float*)d_in[4];
    const float* b1 = (const float*)d_in[5];
    const float* W2 = (const float*)d_in[6];
    const float* b2 = (const float*)d_in[7];
    const float* Wo = (const float*)d_in[8];
    const float* bo = (const float*)d_in[9];
    float* out = (float*)d_out;

    const int E = in_sizes[1] / 2;
    const int N = NN;
    const int* srcp = ei;
    const int* dstp = ei + E;

    // workspace layout (h/P/Q all f16 now)
    unsigned short* h  = (unsigned short*)d_ws;               // N*HID f16
    unsigned short* Pb = h + (size_t)N * HID;                 // N*HID f16
    unsigned short* Qb = Pb + (size_t)N * HID;                // N*HID f16
    int* cntc   = (int*)(Qb + (size_t)N * HID);               // CH*NB
    int* basec  = cntc + CH * NB;                             // CH*NB
    int* bincnt = basec + CH * NB;                            // NB
    int* binoff = bincnt + NB;                                // NB
    int2* meta  = (int2*)(binoff + NB);                       // N
    unsigned* bscratch = (unsigned*)(meta + N);               // E
    unsigned short* csr = (unsigned short*)(bscratch + E);    // E ushort

    const int CE = (E + CH - 1) / CH;

    k_hist<<<CH, 256, 0, stream>>>(dstp, cntc, E, CE);
    k_base<<<(NB + 255) / 256, 256, 0, stream>>>(cntc, basec, bincnt);
    k_binscan<<<1, 256, 0, stream>>>(bincnt, binoff);
    k_scatter<<<CH * NPART, 256, 0, stream>>>(srcp, dstp, basec, binoff, bscratch, E, CE);
    k_binsort<<<NB, 256, 0, stream>>>(bscratch, bincnt, binoff, csr, meta);

    k_projpq<<<PQ_BLOCKS, 256, 0, stream>>>(x, Wp, bp, W1, b1, h, Pb, Qb);

    const int EDGE_BLOCKS = 2048;
    const int NW = EDGE_BLOCKS * 256 / 64;
    for (int l = 0; l < NLAYERS; l++) {
        if (l > 0)
            k_pq_mfma<<<PQ_BLOCKS, 256, 0, stream>>>(h, W1, b1, Pb, Qb, l);
        k_edge<<<EDGE_BLOCKS, 256, 0, stream>>>(Pb, Qb, W2, b2, meta, csr, h, l, NW,
                                                l == NLAYERS - 1 ? 1 : 0, Wo, bo, out);
    }
}

// Round 17
// 281.780 us; speedup vs baseline: 1.0371x; 1.0371x over previous
//
#include <hip/hip_runtime.h>

#define NN 50000
#define IN_DIM 128
#define HID 64
#define NLAYERS 3
#define NB 1563      // ceil(NN/32) bins (bin = dst>>5)
#define CH 128       // edge chunks
#define NPART 8      // XCD partitions for scatter
#define BPP 196      // bins per partition (8*196 >= NB)
#define PQ_BLOCKS 782

typedef __attribute__((ext_vector_type(8))) _Float16 f16x8;
typedef __attribute__((ext_vector_type(2))) _Float16 f16x2;
typedef __attribute__((ext_vector_type(4))) float f32x4;

__device__ __forceinline__ unsigned pkh(float a, float b) {
    return __builtin_bit_cast(unsigned, __builtin_amdgcn_cvt_pkrtz(a, b));
}
__device__ __forceinline__ unsigned short f2h(float f) {
    f16x2 v = __builtin_bit_cast(f16x2, __builtin_amdgcn_cvt_pkrtz(f, 0.f));
    return __builtin_bit_cast(short2, v).x;
}
__device__ __forceinline__ float h2f(unsigned short u) {
    return (float)__builtin_bit_cast(_Float16, u);
}

// packed f16: relu(q + p) in 2 VALU ops (v_pk_add_f16 + v_pk_max_f16).
__device__ __forceinline__ unsigned addrelu2(unsigned q, unsigned p) {
    f16x2 qq = __builtin_bit_cast(f16x2, q);
    f16x2 pp = __builtin_bit_cast(f16x2, p);
    f16x2 s = qq + pp;
    f16x2 z = {(_Float16)0.f, (_Float16)0.f};
    f16x2 r = __builtin_elementwise_max(s, z);
    return __builtin_bit_cast(unsigned, r);
}

// ---- CSR build (hist fused into k_front; rest = R11 structure) ----

__global__ void k_base(const int* __restrict__ cntc, int* __restrict__ basec,
                       int* __restrict__ bincnt) {
    int b = blockIdx.x * 256 + threadIdx.x;
    if (b < NB) {
        int run = 0;
        for (int g = 0; g < CH; g++) {
            basec[g * NB + b] = run;
            run += cntc[g * NB + b];
        }
        bincnt[b] = run;
    }
}

__global__ void k_binscan(const int* __restrict__ bincnt, int* __restrict__ binoff) {
    __shared__ int s[256];
    int t = threadIdx.x;
    int carry = 0;
    for (int c0 = 0; c0 < NB; c0 += 256) {
        int v = (c0 + t < NB) ? bincnt[c0 + t] : 0;
        s[t] = v;
        __syncthreads();
        for (int d = 1; d < 256; d <<= 1) {
            int a = (t >= d) ? s[t - d] : 0;
            __syncthreads();
            s[t] += a;
            __syncthreads();
        }
        if (c0 + t < NB) binoff[c0 + t] = carry + s[t] - v;
        carry += s[255];
        __syncthreads();
    }
}

__global__ void __launch_bounds__(256) k_scatter(
    const int* __restrict__ src, const int* __restrict__ dst,
    const int* __restrict__ basec, const int* __restrict__ binoff,
    unsigned* __restrict__ bscratch, int E, int CE) {
    __shared__ int cur[BPP];
    int p = blockIdx.x & (NPART - 1);
    int g = blockIdx.x >> 3;
    int blo = p * BPP, bhi = min(NB, blo + BPP);
    for (int i = threadIdx.x; i < bhi - blo; i += 256) {
        int b = blo + i;
        cur[i] = binoff[b] + basec[g * NB + b];
    }
    __syncthreads();
    int e0 = g * CE, e1 = min(E, e0 + CE);
    for (int e = e0 + threadIdx.x; e < e1; e += 256) {
        int d = dst[e];
        int bin = d >> 5;
        if (bin >= blo && bin < bhi) {
            int pos = atomicAdd(&cur[bin - blo], 1);
            bscratch[pos] = ((unsigned)(d & 31) << 16) | (unsigned)src[e];
        }
    }
}

__global__ void __launch_bounds__(256) k_binsort(
    const unsigned* __restrict__ bscratch, const int* __restrict__ bincnt,
    const int* __restrict__ binoff, unsigned short* __restrict__ csr,
    int2* __restrict__ meta) {
    __shared__ unsigned entries[1024];
    __shared__ unsigned short sorted[1024];
    __shared__ int cnt[32];
    int bin = blockIdx.x, t = threadIdx.x;
    int n = bincnt[bin], boff = binoff[bin];
    for (int i = t; i < n; i += 256) entries[i] = bscratch[boff + i];
    if (t < 32) cnt[t] = 0;
    __syncthreads();
    for (int i = t; i < n; i += 256) atomicAdd(&cnt[entries[i] >> 16], 1);
    __syncthreads();
    if (t < 32) {
        int c = cnt[t];
        int s = c;
#pragma unroll
        for (int d = 1; d < 32; d <<= 1) {
            int o = __shfl_up(s, d, 64);
            if (t >= d) s += o;
        }
        int node = bin * 32 + t;
        if (node < NN) meta[node] = make_int2(boff + s - c, c);
        cnt[t] = s - c;  // reuse as cursor
    }
    __syncthreads();
    for (int i = t; i < n; i += 256) {
        unsigned e = entries[i];
        int p = atomicAdd(&cnt[e >> 16], 1);
        sorted[p] = (unsigned short)(e & 0xffffu);
    }
    __syncthreads();
    for (int i = t; i < n; i += 256) csr[boff + i] = sorted[i];
}

// ---- fused front: blocks [0,PQ_BLOCKS) = projpq, rest = edge histogram ----
// projpq: h = x@Wp+bp (MFMA, x->f16), then layer-0
// [P|Q] = h@[W1t-W1b | W1b]+[b1|0] (MFMA). h/P/Q stored f16.
__global__ void __launch_bounds__(256) k_front(
    const float* __restrict__ x, const float* __restrict__ Wp,
    const float* __restrict__ bp, const float* __restrict__ W1,
    const float* __restrict__ b1, unsigned short* __restrict__ h,
    unsigned short* __restrict__ P, unsigned short* __restrict__ Qb,
    const int* __restrict__ dst, int* __restrict__ cntc, int E, int CE) {
    __shared__ char smraw[4 * 16 * 66 * 4];  // 16.9 KB, overlaid per branch

    if (blockIdx.x >= PQ_BLOCKS) {
        // ---- histogram branch ----
        int* lh = (int*)smraw;
        int g = blockIdx.x - PQ_BLOCKS;
        for (int i = threadIdx.x; i < NB; i += 256) lh[i] = 0;
        __syncthreads();
        int e0 = g * CE, e1 = min(E, e0 + CE);
        for (int e = e0 + threadIdx.x; e < e1; e += 256) atomicAdd(&lh[dst[e] >> 5], 1);
        __syncthreads();
        for (int i = threadIdx.x; i < NB; i += 256) cntc[g * NB + i] = lh[i];
        return;
    }

    // ---- projpq branch (no barriers; hs rows are wave-private) ----
    float (*hs)[16][66] = (float (*)[16][66])smraw;
    int lane = threadIdx.x & 63, wave = threadIdx.x >> 6;
    int col = lane & 15, quad = lane >> 4;
    int node0 = (blockIdx.x * 4 + wave) * 16;
    if (node0 >= NN) return;  // wave-uniform

    f16x8 bw[4][4];
#pragma unroll
    for (int t = 0; t < 4; t++)
#pragma unroll
        for (int kc = 0; kc < 4; kc++) {
            uint4 u;
#pragma unroll
            for (int jp = 0; jp < 4; jp++) {
                int k0 = kc * 32 + quad * 8 + jp * 2;
                ((unsigned*)&u)[jp] = pkh(Wp[k0 * HID + t * 16 + col],
                                          Wp[(k0 + 1) * HID + t * 16 + col]);
            }
            bw[t][kc] = __builtin_bit_cast(f16x8, u);
        }
    const float4* xr = (const float4*)(x + (size_t)(node0 + col) * IN_DIM);
    f16x8 ax[4];
#pragma unroll
    for (int kc = 0; kc < 4; kc++) {
        float4 f0 = xr[kc * 8 + quad * 2], f1 = xr[kc * 8 + quad * 2 + 1];
        uint4 u;
        u.x = pkh(f0.x, f0.y); u.y = pkh(f0.z, f0.w);
        u.z = pkh(f1.x, f1.y); u.w = pkh(f1.z, f1.w);
        ax[kc] = __builtin_bit_cast(f16x8, u);
    }
#pragma unroll
    for (int t = 0; t < 4; t++) {
        f32x4 c = (f32x4)(0.f);
#pragma unroll
        for (int kc = 0; kc < 4; kc++)
            c = __builtin_amdgcn_mfma_f32_16x16x32_f16(ax[kc], bw[t][kc], c, 0, 0, 0);
        float bv = bp[t * 16 + col];
#pragma unroll
        for (int r = 0; r < 4; r++) {
            float hv = c[r] + bv;
            int row = quad * 4 + r;
            h[(size_t)(node0 + row) * HID + t * 16 + col] = f2h(hv);
            hs[wave][row][t * 16 + col] = hv;
        }
    }

    f16x8 bfr[8][2];
#pragma unroll
    for (int t = 0; t < 8; t++)
#pragma unroll
        for (int hf = 0; hf < 2; hf++) {
            uint4 u;
#pragma unroll
            for (int jp = 0; jp < 4; jp++) {
                int k0 = hf * 32 + quad * 8 + jp * 2;
                float w0, w1v;
                if (t < 4) {
                    int n = t * 16 + col;
                    w0  = W1[k0 * HID + n] - W1[(HID + k0) * HID + n];
                    w1v = W1[(k0 + 1) * HID + n] - W1[(HID + k0 + 1) * HID + n];
                } else {
                    int n = (t - 4) * 16 + col;
                    w0  = W1[(HID + k0) * HID + n];
                    w1v = W1[(HID + k0 + 1) * HID + n];
                }
                ((unsigned*)&u)[jp] = pkh(w0, w1v);
            }
            bfr[t][hf] = __builtin_bit_cast(f16x8, u);
        }
    const float* hl = &hs[wave][col][0];
    uint4 au, bu;
    {
        float2 e0 = *(const float2*)(hl + quad * 8);
        float2 e1 = *(const float2*)(hl + quad * 8 + 2);
        float2 e2 = *(const float2*)(hl + quad * 8 + 4);
        float2 e3 = *(const float2*)(hl + quad * 8 + 6);
        au.x = pkh(e0.x, e0.y); au.y = pkh(e1.x, e1.y);
        au.z = pkh(e2.x, e2.y); au.w = pkh(e3.x, e3.y);
        float2 f0 = *(const float2*)(hl + 32 + quad * 8);
        float2 f1 = *(const float2*)(hl + 32 + quad * 8 + 2);
        float2 f2 = *(const float2*)(hl + 32 + quad * 8 + 4);
        float2 f3 = *(const float2*)(hl + 32 + quad * 8 + 6);
        bu.x = pkh(f0.x, f0.y); bu.y = pkh(f1.x, f1.y);
        bu.z = pkh(f2.x, f2.y); bu.w = pkh(f3.x, f3.y);
    }
    f16x8 a0 = __builtin_bit_cast(f16x8, au);
    f16x8 a1 = __builtin_bit_cast(f16x8, bu);
#pragma unroll
    for (int t = 0; t < 8; t++) {
        f32x4 c = __builtin_amdgcn_mfma_f32_16x16x32_f16(a0, bfr[t][0], (f32x4)(0.f), 0, 0, 0);
        c = __builtin_amdgcn_mfma_f32_16x16x32_f16(a1, bfr[t][1], c, 0, 0, 0);
        if (t < 4) {
            float bv = b1[t * 16 + col];
#pragma unroll
            for (int r = 0; r < 4; r++)
                P[(size_t)(node0 + quad * 4 + r) * HID + t * 16 + col] = f2h(c[r] + bv);
        } else {
#pragma unroll
            for (int r = 0; r < 4; r++)
                Qb[(size_t)(node0 + quad * 4 + r) * HID + (t - 4) * 16 + col] = f2h(c[r]);
        }
    }
}

// [P|Q] = h @ [W1top-W1bot | W1bot] + [b1|0] via MFMA (layers 1,2).
// h is f16: A-fragments are direct uint4 reinterprets of the h row.
__global__ void __launch_bounds__(256) k_pq_mfma(
    const unsigned short* __restrict__ h, const float* __restrict__ W1,
    const float* __restrict__ b1, unsigned short* __restrict__ P,
    unsigned short* __restrict__ Qb, int layer) {
    int lane = threadIdx.x & 63, wave = threadIdx.x >> 6;
    int col = lane & 15, quad = lane >> 4;
    int node0 = (blockIdx.x * 4 + wave) * 16;
    if (node0 >= NN) return;
    const float* W1l = W1 + layer * 2 * HID * HID;

    f16x8 bfr[8][2];
#pragma unroll
    for (int t = 0; t < 8; t++)
#pragma unroll
        for (int hf = 0; hf < 2; hf++) {
            uint4 u;
#pragma unroll
            for (int jp = 0; jp < 4; jp++) {
                int k0 = hf * 32 + quad * 8 + jp * 2;
                float w0, w1v;
                if (t < 4) {
                    int n = t * 16 + col;
                    w0  = W1l[k0 * HID + n] - W1l[(HID + k0) * HID + n];
                    w1v = W1l[(k0 + 1) * HID + n] - W1l[(HID + k0 + 1) * HID + n];
                } else {
                    int n = (t - 4) * 16 + col;
                    w0  = W1l[(HID + k0) * HID + n];
                    w1v = W1l[(HID + k0 + 1) * HID + n];
                }
                ((unsigned*)&u)[jp] = pkh(w0, w1v);
            }
            bfr[t][hf] = __builtin_bit_cast(f16x8, u);
        }

    const uint4* hrow = (const uint4*)(h + (size_t)(node0 + col) * HID);
    uint4 au = hrow[quad];      // k in [quad*8, +8)
    uint4 bu = hrow[4 + quad];  // k in [32+quad*8, +8)
    f16x8 a0 = __builtin_bit_cast(f16x8, au);
    f16x8 a1 = __builtin_bit_cast(f16x8, bu);

#pragma unroll
    for (int t = 0; t < 8; t++) {
        f32x4 c = __builtin_amdgcn_mfma_f32_16x16x32_f16(a0, bfr[t][0], (f32x4)(0.f), 0, 0, 0);
        c = __builtin_amdgcn_mfma_f32_16x16x32_f16(a1, bfr[t][1], c, 0, 0, 0);
        if (t < 4) {
            float bv = b1[layer * HID + t * 16 + col];
#pragma unroll
            for (int r = 0; r < 4; r++)
                P[(size_t)(node0 + quad * 4 + r) * HID + t * 16 + col] = f2h(c[r] + bv);
        } else {
#pragma unroll
            for (int r = 0; r < 4; r++)
                Qb[(size_t)(node0 + quad * 4 + r) * HID + (t - 4) * 16 + col] = f2h(c[r]);
        }
    }
}

// One wave per dst node (grid-stride). 16 edges/batch via mfma_f32_16x16x32_f16.
// R15's staged gather: full-row dwordx4 gathers -> one-deep register prefetch
// -> per-wave LDS row stage -> A-layout reads. Node-level meta/res prefetch.
__global__ void __launch_bounds__(256) k_edge(
    const unsigned short* __restrict__ P, const unsigned short* __restrict__ Qb,
    const float* __restrict__ W2, const float* __restrict__ b2,
    const int2* __restrict__ meta, const unsigned short* __restrict__ csr,
    unsigned short* __restrict__ h, int layer, int nw,
    int fin, const float* __restrict__ Wo, const float* __restrict__ bo,
    float* __restrict__ outp) {
    __shared__ uint4 qstage[4][16][9];  // 9216B: per-wave row stage (stride 144B)
    int lane = threadIdx.x & 63;
    int col = lane & 15, quad = lane >> 4;
    int wave = threadIdx.x >> 6;
    int rrow = lane >> 3, sseg = lane & 7;  // full-row gather mapping
    int wid = (blockIdx.x * blockDim.x + threadIdx.x) >> 6;

    const float* W2l = W2 + layer * HID * HID;
    f16x8 bfr[4][2];
#pragma unroll
    for (int t = 0; t < 4; t++)
#pragma unroll
        for (int hf = 0; hf < 2; hf++) {
            uint4 u;
#pragma unroll
            for (int jp = 0; jp < 4; jp++) {
                int k0 = hf * 32 + quad * 8 + jp * 2;
                ((unsigned*)&u)[jp] = pkh(W2l[k0 * HID + t * 16 + col],
                                          W2l[(k0 + 1) * HID + t * 16 + col]);
            }
            bfr[t][hf] = __builtin_bit_cast(f16x8, u);
        }
    float b2v = b2[layer * HID + lane];
    float wov = fin ? Wo[lane] : 0.f;

    if (wid >= NN) return;
    int2 md = meta[wid];
    unsigned short hres = h[(size_t)wid * HID + lane];

    for (int node = wid; node < NN; node += nw) {
        // prefetch next node's meta + residual (independent of current work)
        int pf = (node + nw < NN) ? node + nw : node;
        int2 nmd = meta[pf];
        unsigned short nhres = h[(size_t)pf * HID + lane];

        int start = __builtin_amdgcn_readfirstlane(md.x);
        int cnt   = __builtin_amdgcn_readfirstlane(md.y);
        float res = h2f(hres);
        float outv = 0.f;
        if (cnt > 0) {
            const uint4* prow = (const uint4*)(P + (size_t)node * HID);
            uint4 p0 = prow[quad];      // k in [quad*8, +8)
            uint4 p1 = prow[4 + quad];  // k in [32+quad*8, +8)
            f32x4 mx[4];
#pragma unroll
            for (int t = 0; t < 4; t++) mx[t] = (f32x4)(-3.4e38f);
            int nbatch = (cnt + 15) >> 4;
            // prologue: gather batch 0 into registers (full-row mapping)
            uint4 v1, v2;
            {
                int e1 = rrow, e2 = 8 + rrow;
                int s1 = csr[start + (e1 < cnt ? e1 : 0)];
                int s2 = csr[start + (e2 < cnt ? e2 : 0)];
                v1 = ((const uint4*)(Qb + (size_t)s1 * HID))[sseg];
                v2 = ((const uint4*)(Qb + (size_t)s2 * HID))[sseg];
            }
            for (int b = 0; b < nbatch; b++) {
                // stage batch b (vmcnt wait here, overlapped w/ prev compute)
                qstage[wave][rrow][sseg] = v1;
                qstage[wave][8 + rrow][sseg] = v2;
                // issue batch b+1's gathers (async)
                if (b + 1 < nbatch) {
                    int b0 = (b + 1) * 16;
                    int e1 = b0 + rrow, e2 = b0 + 8 + rrow;
                    int s1 = csr[start + (e1 < cnt ? e1 : b0)];
                    int s2 = csr[start + (e2 < cnt ? e2 : b0)];
                    v1 = ((const uint4*)(Qb + (size_t)s1 * HID))[sseg];
                    v2 = ((const uint4*)(Qb + (size_t)s2 * HID))[sseg];
                }
                // consume batch b from the stage
                uint4 q0 = qstage[wave][col][quad];      // k in [quad*8, +8)
                uint4 q1 = qstage[wave][col][4 + quad];  // k in [32+quad*8, +8)
                uint4 a0u, a1u;
                a0u.x = addrelu2(q0.x, p0.x);
                a0u.y = addrelu2(q0.y, p0.y);
                a0u.z = addrelu2(q0.z, p0.z);
                a0u.w = addrelu2(q0.w, p0.w);
                a1u.x = addrelu2(q1.x, p1.x);
                a1u.y = addrelu2(q1.y, p1.y);
                a1u.z = addrelu2(q1.z, p1.z);
                a1u.w = addrelu2(q1.w, p1.w);
                f16x8 a0 = __builtin_bit_cast(f16x8, a0u);
                f16x8 a1 = __builtin_bit_cast(f16x8, a1u);
#pragma unroll
                for (int t = 0; t < 4; t++) {
                    f32x4 c = __builtin_amdgcn_mfma_f32_16x16x32_f16(
                        a0, bfr[t][0], (f32x4)(0.f), 0, 0, 0);
                    c = __builtin_amdgcn_mfma_f32_16x16x32_f16(
                        a1, bfr[t][1], c, 0, 0, 0);
#pragma unroll
                    for (int r = 0; r < 4; r++)
                        mx[t][r] = fmaxf(mx[t][r], c[r]);
                }
            }
            float v[4];
#pragma unroll
            for (int t = 0; t < 4; t++) {
                v[t] = fmaxf(fmaxf(mx[t][0], mx[t][1]), fmaxf(mx[t][2], mx[t][3]));
                v[t] = fmaxf(v[t], __shfl_xor(v[t], 16, 64));
                v[t] = fmaxf(v[t], __shfl_xor(v[t], 32, 64));
            }
            float vs = quad == 0 ? v[0] : quad == 1 ? v[1] : quad == 2 ? v[2] : v[3];
            outv = fmaxf(vs + b2v, 0.f);
        }
        float hv = outv + res;
        h[(size_t)node * HID + lane] = f2h(hv);
        if (fin) {
            float v = hv * wov;
#pragma unroll
            for (int m = 32; m >= 1; m >>= 1) v += __shfl_xor(v, m, 64);
            if (lane == 0) outp[node] = v + bo[0];
        }
        md = nmd;
        hres = nhres;
    }
}

extern "C" void kernel_launch(void* const* d_in, const int* in_sizes, int n_in,
                              void* d_out, int out_size, void* d_ws, size_t ws_size,
                              hipStream_t stream) {
    const float* x  = (const float*)d_in[0];
    const int*   ei = (const int*)d_in[1];
    const float* Wp = (const float*)d_in[2];
    const float* bp = (const float*)d_in[3];
    const float* W1 = (const float*)d_in[4];
    const float* b1 = (const float*)d_in[5];
    const float* W2 = (const float*)d_in[6];
    const float* b2 = (const float*)d_in[7];
    const float* Wo = (const float*)d_in[8];
    const float* bo = (const float*)d_in[9];
    float* out = (float*)d_out;

    const int E = in_sizes[1] / 2;
    const int N = NN;
    const int* srcp = ei;
    const int* dstp = ei + E;

    // workspace layout (h/P/Q all f16)
    unsigned short* h  = (unsigned short*)d_ws;               // N*HID f16
    unsigned short* Pb = h + (size_t)N * HID;                 // N*HID f16
    unsigned short* Qb = Pb + (size_t)N * HID;                // N*HID f16
    int* cntc   = (int*)(Qb + (size_t)N * HID);               // CH*NB
    int* basec  = cntc + CH * NB;                             // CH*NB
    int* bincnt = basec + CH * NB;                            // NB
    int* binoff = bincnt + NB;                                // NB
    int2* meta  = (int2*)(binoff + NB);                       // N
    unsigned* bscratch = (unsigned*)(meta + N);               // E
    unsigned short* csr = (unsigned short*)(bscratch + E);    // E ushort

    const int CE = (E + CH - 1) / CH;

    // fused projpq + hist: dense front and CSR chain start together
    k_front<<<PQ_BLOCKS + CH, 256, 0, stream>>>(x, Wp, bp, W1, b1, h, Pb, Qb,
                                                dstp, cntc, E, CE);
    k_base<<<(NB + 255) / 256, 256, 0, stream>>>(cntc, basec, bincnt);
    k_binscan<<<1, 256, 0, stream>>>(bincnt, binoff);
    k_scatter<<<CH * NPART, 256, 0, stream>>>(srcp, dstp, basec, binoff, bscratch, E, CE);
    k_binsort<<<NB, 256, 0, stream>>>(bscratch, bincnt, binoff, csr, meta);

    const int EDGE_BLOCKS = 2048;
    const int NW = EDGE_BLOCKS * 256 / 64;
    for (int l = 0; l < NLAYERS; l++) {
        if (l > 0)
            k_pq_mfma<<<PQ_BLOCKS, 256, 0, stream>>>(h, W1, b1, Pb, Qb, l);
        k_edge<<<EDGE_BLOCKS, 256, 0, stream>>>(Pb, Qb, W2, b2, meta, csr, h, l, NW,
                                                l == NLAYERS - 1 ? 1 : 0, Wo, bo, out);
    }
}